// Round 3
// baseline (481.375 us; speedup 1.0000x reference)
//
#include <hip/hip_runtime.h>
#include <math.h>

// Problem constants
#define NB 128
#define NR 512
#define NC 81
#define NDK 64
#define NRK 10
#define NROWS (NB * NR)  // 65536

#define LOG2E 1.44269504088896340736f

// ---------------------------------------------------------------------------
// Kernel A: per-row q/k projection + label (argmax) + xmax (row max).
// ---------------------------------------------------------------------------
#define KA_ROWS 32
#define KA_THREADS 128

__global__ __launch_bounds__(KA_THREADS, 4) void qk_label_kernel(
    const float* __restrict__ x,
    const float* __restrict__ Wq, const float* __restrict__ bq,
    const float* __restrict__ Wk, const float* __restrict__ bk,
    float* __restrict__ Q, float* __restrict__ K,
    int* __restrict__ label, float* __restrict__ xmax)
{
    __shared__ float xl[KA_ROWS][84];

    const int t = threadIdx.x;
    const int d = t & 63;
    const bool isK = t >= 64;
    const float* W = isK ? Wk : Wq;
    const float bias = (isK ? bk : bq)[d];

    float w[84];
#pragma unroll
    for (int c = 0; c < 81; ++c) w[c] = W[c * 64 + d];
    w[81] = 0.f; w[82] = 0.f; w[83] = 0.f;

    const int r0 = blockIdx.x * KA_ROWS;

    for (int e = t; e < KA_ROWS * 84; e += KA_THREADS) {
        int r = e / 84;
        int c = e - r * 84;
        xl[r][c] = (c < 81) ? x[(size_t)(r0 + r) * NC + c] : 0.f;
    }
    __syncthreads();

    if (t < KA_ROWS) {
        float bv = -INFINITY; int bi = 0;
#pragma unroll
        for (int c = 0; c < 81; ++c) {
            float v = xl[t][c];
            if (v > bv) { bv = v; bi = c; }
        }
        label[r0 + t] = bi;
        xmax[r0 + t] = bv;
    }

    float* OUT = isK ? K : Q;
    for (int r = 0; r < KA_ROWS; ++r) {
        const float4* xr = reinterpret_cast<const float4*>(&xl[r][0]);
        float a0 = 0.f, a1 = 0.f, a2 = 0.f, a3 = 0.f;
#pragma unroll
        for (int c4 = 0; c4 < 21; ++c4) {
            float4 xv = xr[c4];
            a0 = fmaf(xv.x, w[c4 * 4 + 0], a0);
            a1 = fmaf(xv.y, w[c4 * 4 + 1], a1);
            a2 = fmaf(xv.z, w[c4 * 4 + 2], a2);
            a3 = fmaf(xv.w, w[c4 * 4 + 3], a3);
        }
        OUT[(size_t)(r0 + r) * NDK + d] = (a0 + a1) + (a2 + a3) + bias;
    }
}

// ---------------------------------------------------------------------------
// Kernel B: attention + softmax-denominator + top-10 + sparse FC.
// Grid: 256 blocks (128 batches x 2 row-halves). Block: 512 threads = 8 waves
//   = 4 row-groups (64 rows each, lane<->row) x 2 j-halves (256 j's each).
// Partial (lsum, top-10) per j-half merged via LDS two-pointer merge.
// No online max: scores are O(7), exp2 of raw scores is safe in f32.
// ---------------------------------------------------------------------------
__global__ __launch_bounds__(512, 2) void attn_kernel(
    const float* __restrict__ Q, const float* __restrict__ K,
    const int* __restrict__ label, const float* __restrict__ xmax,
    const float* __restrict__ Wfc, const float* __restrict__ bfc,
    const float* __restrict__ prior, float* __restrict__ out)
{
    __shared__ float WfcS[NC * NC];   // 26.2 KB
    __shared__ float bfcS[NC];
    __shared__ int   labS[NR];        // 2 KB
    __shared__ float xmS[NR];         // 2 KB
    __shared__ union U {
        float4 kl[2][64 * 16];        // 2 chunks x 64 rows x 64 f32 = 32 KB
        struct {
            float tv[2][256][10];     // 20 KB
            int   ti[2][256][10];     // 20 KB
            float ls[2][256];         // 2 KB
        } p;
    } u;

    const int t    = threadIdx.x;
    const int b    = blockIdx.x >> 1;
    const int half = blockIdx.x & 1;
    const int lane = t & 63;
    const int wv   = t >> 6;        // 0..7
    const int rg   = wv & 3;        // row group
    const int jh   = wv >> 2;       // j half
    const int rb   = rg * 64 + lane;        // row within block's 256
    const int r    = half * 256 + rb;       // row within batch
    const int g    = b * NR + r;            // global row

    for (int e = t; e < NC * NC; e += 512) WfcS[e] = Wfc[e];
    if (t < NC) bfcS[t] = bfc[t];
    if (t < NR) { labS[t] = label[b * NR + t]; xmS[t] = xmax[b * NR + t]; }

    // q row into registers
    float q[64];
    {
        const float4* qg = reinterpret_cast<const float4*>(&Q[(size_t)g * NDK]);
#pragma unroll
        for (int i = 0; i < 16; ++i) {
            float4 v = qg[i];
            q[4 * i + 0] = v.x; q[4 * i + 1] = v.y; q[4 * i + 2] = v.z; q[4 * i + 3] = v.w;
        }
    }

    float lsum = 0.f;
    float tv[10]; int ti[10];
#pragma unroll
    for (int i = 0; i < 10; ++i) { tv[i] = -INFINITY; ti[i] = 0; }

    // staging thread mapping: chunk c0 = t>>8, tt = t&255 loads 4 float4
    const int c0 = t >> 8;
    const int tt = t & 255;

    __syncthreads();

    for (int step = 0; step < 4; ++step) {
        if (step) __syncthreads();  // previous chunk fully consumed
        {
            const float4* kg = reinterpret_cast<const float4*>(
                &K[(size_t)(b * NR + c0 * 256 + step * 64) * NDK]);
            float4* kls = u.kl[c0];
#pragma unroll
            for (int s = 0; s < 4; ++s) kls[tt + 256 * s] = kg[tt + 256 * s];
        }
        __syncthreads();

        const int jbase = jh * 256 + step * 64;
#pragma unroll 4
        for (int jj = 0; jj < 64; ++jj) {
            const float4* kj = &u.kl[jh][jj * 16];
            float s0 = 0.f, s1 = 0.f, s2 = 0.f, s3 = 0.f;
#pragma unroll
            for (int d4 = 0; d4 < 16; ++d4) {
                float4 kv = kj[d4];
                s0 = fmaf(q[4 * d4 + 0], kv.x, s0);
                s1 = fmaf(q[4 * d4 + 1], kv.y, s1);
                s2 = fmaf(q[4 * d4 + 2], kv.z, s2);
                s3 = fmaf(q[4 * d4 + 3], kv.w, s3);
            }
            float sc = ((s0 + s1) + (s2 + s3)) * 0.125f;  // 1/sqrt(64)

            lsum += exp2f(sc * LOG2E);

            // sorted top-10 insert; strict > keeps (value desc, index asc)
            if (sc > tv[9]) {
                const int j = jbase + jj;
#pragma unroll
                for (int i = 9; i >= 1; --i) {
                    bool sh = sc > tv[i - 1];
                    float nv = sh ? tv[i - 1] : sc;
                    int   ni = sh ? ti[i - 1] : j;
                    if (sc > tv[i]) { tv[i] = nv; ti[i] = ni; }
                }
                if (sc > tv[0]) { tv[0] = sc; ti[0] = j; }
            }
        }
    }

    // publish partials
    __syncthreads();  // all compute reads of u.kl done before union reuse
#pragma unroll
    for (int i = 0; i < 10; ++i) {
        u.p.tv[jh][rb][i] = tv[i];
        u.p.ti[jh][rb][i] = ti[i];
    }
    u.p.ls[jh][rb] = lsum;
    __syncthreads();

    if (jh == 0) {
        // merge two sorted lists (A indices < B indices; >= prefers A on ties)
        const float inv = 1.f / (u.p.ls[0][rb] + u.p.ls[1][rb]);
        float mtv[10]; int mti[10];
        int ia = 0, ib = 0;
#pragma unroll
        for (int s = 0; s < 10; ++s) {
            float av = u.p.tv[0][rb][ia];
            float bv = u.p.tv[1][rb][ib];
            bool ta = av >= bv;
            mtv[s] = ta ? av : bv;
            mti[s] = ta ? u.p.ti[0][rb][ia] : u.p.ti[1][rb][ib];
            ia += ta ? 1 : 0;
            ib += ta ? 0 : 1;
        }

        const int li = labS[r];
        float cv[10]; int lj[10];
#pragma unroll
        for (int k2 = 0; k2 < 10; ++k2) {
            int j = mti[k2];
            int l = labS[j];
            float val = exp2f(mtv[k2] * LOG2E) * inv;
            cv[k2] = (l != li) ? prior[l * NC + li] * val * xmS[j] : 0.f;
            lj[k2] = l;
        }
        // merge duplicate labels into first occurrence
#pragma unroll
        for (int a2 = 1; a2 < 10; ++a2) {
#pragma unroll
            for (int b2 = 0; b2 < a2; ++b2) {
                if (lj[a2] == lj[b2]) { cv[b2] += cv[a2]; cv[a2] = 0.f; break; }
            }
        }
#pragma unroll
        for (int k2 = 0; k2 < 10; ++k2) cv[k2] = fmaxf(cv[k2], 0.f);

        float* og = &out[(size_t)g * NC];
        for (int c = 0; c < NC; ++c) {
            float z = bfcS[c];
#pragma unroll
            for (int k2 = 0; k2 < 10; ++k2) z = fmaf(cv[k2], WfcS[lj[k2] * NC + c], z);
            og[c] = 1.f / (1.f + exp2f(-z * LOG2E));
        }
    }
}

// ---------------------------------------------------------------------------
extern "C" void kernel_launch(void* const* d_in, const int* in_sizes, int n_in,
                              void* d_out, int out_size, void* d_ws, size_t ws_size,
                              hipStream_t stream)
{
    const float* x     = (const float*)d_in[0];
    const float* Wq    = (const float*)d_in[1];
    const float* bq    = (const float*)d_in[2];
    const float* Wk    = (const float*)d_in[3];
    const float* bk    = (const float*)d_in[4];
    const float* Wfc   = (const float*)d_in[5];
    const float* bfc   = (const float*)d_in[6];
    const float* prior = (const float*)d_in[7];
    float* out = (float*)d_out;

    float* Q     = (float*)d_ws;
    float* K     = Q + (size_t)NROWS * NDK;
    int*   label = (int*)(K + (size_t)NROWS * NDK);
    float* xmax  = (float*)(label + NROWS);

    qk_label_kernel<<<NROWS / KA_ROWS, KA_THREADS, 0, stream>>>(
        x, Wq, bq, Wk, bk, Q, K, label, xmax);

    attn_kernel<<<NB * 2, 512, 0, stream>>>(
        Q, K, label, xmax, Wfc, bfc, prior, out);
}

// Round 4
// 281.641 us; speedup vs baseline: 1.7092x; 1.7092x over previous
//
#include <hip/hip_runtime.h>
#include <math.h>
#include <stdint.h>

// Problem constants
#define NB 128
#define NR 512
#define NC 81
#define NDK 64
#define NROWS (NB * NR)  // 65536
#define LOG2E 1.44269504088896340736f

// ---------------------------------------------------------------------------
// Kernel A v2: per-row q/k projection + label (argmax) + xmax (row max).
// Outer-product register tile: 256 threads = 32 col-groups (4 outs) x 8 row
// groups (8 rows). acc[8][4] ~ 55 VGPR -> no spill under any heuristic.
// x rows + [Wq|Wk] staged in LDS; x read as 2-distinct-addr broadcast,
// W read as per-lane-distinct b128 (bank-optimal 512B/wave).
// ---------------------------------------------------------------------------
__global__ __launch_bounds__(256) void qk_label_kernel(
    const float* __restrict__ x,
    const float* __restrict__ Wq, const float* __restrict__ bq,
    const float* __restrict__ Wk, const float* __restrict__ bk,
    float* __restrict__ Q, float* __restrict__ K,
    int* __restrict__ label, float* __restrict__ xmax)
{
    __shared__ float xS[64][84];       // 21.5 KB (pad 84 vs bank stride)
    __shared__ float WallS[81][128];   // 41.5 KB  [c][Wq d | Wk d]

    const int t = threadIdx.x;
    const int r0 = blockIdx.x * 64;
    const int d4 = t & 31;    // output col group (4 cols)
    const int rgrp = t >> 5;  // row group (8 rows)

    // stage x: 64 rows x 81 f32, coalesced; magic div by 81 (valid < 20971)
#pragma unroll
    for (int k = 0; k < 21; ++k) {
        int flat = t + 256 * k;
        if (flat < 64 * 81) {
            int rr = (int)(((unsigned)flat * 6473u) >> 19);
            int cc = flat - 81 * rr;
            xS[rr][cc] = x[(size_t)r0 * NC + flat];
        }
    }
    // stage Wall = [Wq | Wk] as [c][128]
#pragma unroll
    for (int k = 0; k < 41; ++k) {
        int idx = t + 256 * k;
        if (idx < 81 * 128) {
            int cc = idx >> 7, dd = idx & 127;
            WallS[cc][dd] = (dd < 64) ? Wq[cc * 64 + dd] : Wk[cc * 64 + (dd - 64)];
        }
    }
    __syncthreads();

    // wave 0: labels / row max (first occurrence on ties, like jnp.argmax)
    if (t < 64) {
        float bv = -INFINITY; int bi = 0;
        for (int c = 0; c < 81; ++c) {
            float v = xS[t][c];
            if (v > bv) { bv = v; bi = c; }
        }
        label[r0 + t] = bi;
        xmax[r0 + t] = bv;
    }

    float acc[8][4];
#pragma unroll
    for (int i = 0; i < 8; ++i)
#pragma unroll
        for (int k = 0; k < 4; ++k) acc[i][k] = 0.f;

#pragma unroll 3
    for (int c = 0; c < 81; ++c) {
        const float4 wv = *reinterpret_cast<const float4*>(&WallS[c][d4 * 4]);
#pragma unroll
        for (int i = 0; i < 8; ++i) {
            const float xv = xS[rgrp * 8 + i][c];
            acc[i][0] = fmaf(xv, wv.x, acc[i][0]);
            acc[i][1] = fmaf(xv, wv.y, acc[i][1]);
            acc[i][2] = fmaf(xv, wv.z, acc[i][2]);
            acc[i][3] = fmaf(xv, wv.w, acc[i][3]);
        }
    }

    const bool isQ = (d4 < 16);
    const int ocol = (isQ ? d4 : d4 - 16) * 4;
    const float* bias = isQ ? bq : bk;
    const float b0 = bias[ocol + 0], b1 = bias[ocol + 1];
    const float b2 = bias[ocol + 2], b3 = bias[ocol + 3];
    float* OUT = isQ ? Q : K;
#pragma unroll
    for (int i = 0; i < 8; ++i) {
        float4 o;
        o.x = acc[i][0] + b0; o.y = acc[i][1] + b1;
        o.z = acc[i][2] + b2; o.w = acc[i][3] + b3;
        *reinterpret_cast<float4*>(&OUT[(size_t)(r0 + rgrp * 8 + i) * NDK + ocol]) = o;
    }
}

// ---------------------------------------------------------------------------
// Kernel B v2: attention scores + softmax denom + top-10 + sparse FC.
// Grid: 512 blocks (128 batches x 4 row-quarters). Block: 512 threads =
//   8 waves = 2 row-groups (64 rows, lane<->row) x 4 j-quarters (128 j).
// K rows are wave-uniform -> read via SMEM (s_load) thanks to
// readfirstlane; q row per lane in 64 VGPRs. No LDS / barriers in hot loop.
// Top-10 via branchless packed-u32 sorted insert:
//   packed = (orderable_bf16_key << 9) | (511 - j)   (val desc, idx asc).
// ---------------------------------------------------------------------------
__global__ __launch_bounds__(512) void attn_kernel(
    const float* __restrict__ Q, const float* __restrict__ K,
    const int* __restrict__ label, const float* __restrict__ xmax,
    const float* __restrict__ Wfc, const float* __restrict__ bfc,
    const float* __restrict__ prior, float* __restrict__ out)
{
    __shared__ int   labS[NR];
    __shared__ float xmS[NR];
    __shared__ float bfcS[NC];
    __shared__ struct {
        uint32_t plist[4][128][10];  // 20480 B
        float    ls[4][128];         //  2048 B
        float    fcv[128][10];       //  5120 B
        int      flj[128][10];       //  5120 B
        float    WfcS[NC * NC];      // 26244 B
    } u;                             // 59 KB; total ~63.4 KB -> 2 blocks/CU

    const int t = threadIdx.x;
    const int b = blockIdx.x >> 2;
    const int quarter = blockIdx.x & 3;
    const int lane = t & 63;
    const int wv = t >> 6;   // 0..7
    const int rg = wv & 1;   // row group
    const int jq = wv >> 1;  // j quarter
    const int rb = rg * 64 + lane;       // row within block (0..127)
    const int r  = quarter * 128 + rb;   // row within batch
    const int g  = b * NR + r;           // global row

    labS[t < NR ? t : 0] = label[b * NR + (t < NR ? t : 0)];
    xmS[t < NR ? t : 0]  = xmax[b * NR + (t < NR ? t : 0)];
    if (t < NC) bfcS[t] = bfc[t];

    // q row into registers (64 VGPR)
    float q[64];
    {
        const float4* qg = reinterpret_cast<const float4*>(&Q[(size_t)g * NDK]);
#pragma unroll
        for (int i = 0; i < 16; ++i) {
            float4 v = qg[i];
            q[4 * i + 0] = v.x; q[4 * i + 1] = v.y;
            q[4 * i + 2] = v.z; q[4 * i + 3] = v.w;
        }
    }

    // wave-uniform j base, forced into SGPR so K loads scalarize
    const int jq_s = __builtin_amdgcn_readfirstlane(jq);
    const float* krow0 = &K[(size_t)(b * NR + jq_s * 128) * NDK];

    uint32_t tv[10];
#pragma unroll
    for (int i = 0; i < 10; ++i) tv[i] = 0u;
    float lsum = 0.f;

    for (int jj = 0; jj < 128; ++jj) {
        const float* kr = krow0 + (size_t)jj * NDK;  // uniform -> s_load
        float s0 = 0.f, s1 = 0.f, s2 = 0.f, s3 = 0.f;
#pragma unroll
        for (int d = 0; d < 16; ++d) {
            s0 = fmaf(q[4 * d + 0], kr[4 * d + 0], s0);
            s1 = fmaf(q[4 * d + 1], kr[4 * d + 1], s1);
            s2 = fmaf(q[4 * d + 2], kr[4 * d + 2], s2);
            s3 = fmaf(q[4 * d + 3], kr[4 * d + 3], s3);
        }
        const float sc = ((s0 + s1) + (s2 + s3)) * 0.125f;  // 1/sqrt(64)
        lsum += exp2f(sc * LOG2E);

        // pack: RNE f32->bf16, sign-flip to orderable u16, append inv index
        uint32_t bi = __float_as_uint(sc);
        uint32_t kb = (bi + 0x7FFFu + ((bi >> 16) & 1u)) >> 16;
        kb ^= (kb & 0x8000u) ? 0xFFFFu : 0x8000u;
        uint32_t p = (kb << 9) | (uint32_t)(511 - (jq_s * 128 + jj));

        // branchless sorted top-10 insert (10 unconditional CE pairs)
#pragma unroll
        for (int i = 0; i < 10; ++i) {
            uint32_t hi = tv[i] > p ? tv[i] : p;
            uint32_t lo = tv[i] > p ? p : tv[i];
            tv[i] = hi; p = lo;
        }
    }

    // publish partials; stage Wfc concurrently
    __syncthreads();
#pragma unroll
    for (int i = 0; i < 10; ++i) u.plist[jq][rb][i] = tv[i];
    u.ls[jq][rb] = lsum;
    for (int e = t; e < NC * NC; e += 512) u.WfcS[e] = Wfc[e];
    __syncthreads();

    if (jq == 0) {
        // merge the 3 foreign sorted lists into ours (packed keys: exact)
#pragma unroll
        for (int f = 1; f < 4; ++f) {
#pragma unroll
            for (int i2 = 0; i2 < 10; ++i2) {
                uint32_t p = u.plist[f][rb][i2];
#pragma unroll
                for (int i = 0; i < 10; ++i) {
                    uint32_t hi = tv[i] > p ? tv[i] : p;
                    uint32_t lo = tv[i] > p ? p : tv[i];
                    tv[i] = hi; p = lo;
                }
            }
        }
        const float inv = 1.f /
            (u.ls[0][rb] + u.ls[1][rb] + u.ls[2][rb] + u.ls[3][rb]);
        const int li = labS[r];

        float cv[10]; int lj[10];
#pragma unroll
        for (int k2 = 0; k2 < 10; ++k2) {
            uint32_t p = tv[k2];
            int j = 511 - (int)(p & 511u);
            uint32_t kb = p >> 9;
            uint32_t s16 = kb ^ ((kb & 0x8000u) ? 0x8000u : 0xFFFFu);
            float scq = __uint_as_float(s16 << 16);
            float val = exp2f(scq * LOG2E) * inv;
            int l = labS[j];
            cv[k2] = (l != li) ? prior[l * NC + li] * val * xmS[j] : 0.f;
            lj[k2] = l;
        }
        // merge duplicate labels into first occurrence, then relu
#pragma unroll
        for (int a2 = 1; a2 < 10; ++a2)
#pragma unroll
            for (int b2 = 0; b2 < a2; ++b2)
                if (lj[a2] == lj[b2]) { cv[b2] += cv[a2]; cv[a2] = 0.f; break; }
#pragma unroll
        for (int k2 = 0; k2 < 10; ++k2) cv[k2] = fmaxf(cv[k2], 0.f);

#pragma unroll
        for (int k2 = 0; k2 < 10; ++k2) {
            u.fcv[rb][k2] = cv[k2];
            u.flj[rb][k2] = lj[k2];
        }
    }
    __syncthreads();

    // distributed epilogue: 4 threads per row, stride-4 columns
    {
        const int erow = t >> 2;      // 0..127
        const int cq = t & 3;
        const size_t eg = (size_t)(b * NR + quarter * 128 + erow) * NC;
        float ecv[10]; int elj[10];
#pragma unroll
        for (int i = 0; i < 10; ++i) { ecv[i] = u.fcv[erow][i]; elj[i] = u.flj[erow][i]; }
        for (int c = cq; c < NC; c += 4) {
            float z = bfcS[c];
#pragma unroll
            for (int k2 = 0; k2 < 10; ++k2)
                z = fmaf(ecv[k2], u.WfcS[elj[k2] * NC + c], z);
            out[eg + c] = 1.f / (1.f + exp2f(-z * LOG2E));
        }
    }
}

// ---------------------------------------------------------------------------
extern "C" void kernel_launch(void* const* d_in, const int* in_sizes, int n_in,
                              void* d_out, int out_size, void* d_ws, size_t ws_size,
                              hipStream_t stream)
{
    const float* x     = (const float*)d_in[0];
    const float* Wq    = (const float*)d_in[1];
    const float* bq    = (const float*)d_in[2];
    const float* Wk    = (const float*)d_in[3];
    const float* bk    = (const float*)d_in[4];
    const float* Wfc   = (const float*)d_in[5];
    const float* bfc   = (const float*)d_in[6];
    const float* prior = (const float*)d_in[7];
    float* out = (float*)d_out;

    float* Q     = (float*)d_ws;
    float* K     = Q + (size_t)NROWS * NDK;
    int*   label = (int*)(K + (size_t)NROWS * NDK);
    float* xmax  = (float*)(label + NROWS);

    qk_label_kernel<<<NROWS / 64, 256, 0, stream>>>(
        x, Wq, bq, Wk, bk, Q, K, label, xmax);

    attn_kernel<<<NB * 4, 512, 0, stream>>>(
        Q, K, label, xmax, Wfc, bfc, prior, out);
}